// Round 1
// baseline (790.986 us; speedup 1.0000x reference)
//
#include <hip/hip_runtime.h>

// 4-layer GRU stack, B=4096, T=256. Persistent blocks: 256 blocks x 256 thr,
// each block owns 16 batch rows (one M=16 MFMA tile) and loops over time.
// Weights held in registers as MFMA B-fragments (time-invariant).
// Gate-triple column ownership keeps sigmoid/tanh in C-layout registers.
// h state: fp32 in registers (C-layout) + bf16 copy in LDS for A-fragments.

typedef __attribute__((ext_vector_type(8))) __bf16 bf16x8;
typedef __attribute__((ext_vector_type(4))) float f32x4;

#define TT 256
#define FF 20
#define BT 16   // batch rows per block

__device__ __forceinline__ f32x4 mfma16(bf16x8 a, bf16x8 b, f32x4 c) {
  return __builtin_amdgcn_mfma_f32_16x16x32_bf16(a, b, c, 0, 0, 0);
}

__device__ __forceinline__ float sigm(float x) {
  x = fminf(fmaxf(x, -30.f), 30.f);
  float e = __expf(-x);
  return __builtin_amdgcn_rcpf(1.0f + e);
}

__device__ __forceinline__ float tanh_(float x) {
  x = fminf(fmaxf(x, -15.f), 15.f);
  float e = __expf(-2.f * x);
  return (1.f - e) * __builtin_amdgcn_rcpf(1.f + e);
}

// B-operand fragment from global row-major W[K][N].
// Layout (verified m89/m91 family): lane holds n = ncol, k = kbase + j, j=0..7.
__device__ __forceinline__ bf16x8 bfragW(const float* W, int Kreal, int N,
                                         int ncol, int kbase) {
  bf16x8 r;
#pragma unroll
  for (int j = 0; j < 8; ++j) {
    int k = kbase + j;
    r[j] = (__bf16)(k < Kreal ? W[k * N + ncol] : 0.f);
  }
  return r;
}

// A-operand fragment from LDS row-major act[M][stride]:
// lane holds m = lane&15, k = (lane>>4)*8 + j  -> one ds_read_b128.
__device__ __forceinline__ bf16x8 afragL(const __bf16* base, int stride, int m,
                                         int kbase) {
  return *(const bf16x8*)(base + m * stride + kbase);
}

extern "C" __global__ void __launch_bounds__(256)
gru4(const float* __restrict__ inp, const float* __restrict__ Wemb,
     const float* __restrict__ k0, const float* __restrict__ rk0, const float* __restrict__ b0,
     const float* __restrict__ k1, const float* __restrict__ rk1, const float* __restrict__ b1,
     const float* __restrict__ k2, const float* __restrict__ rk2, const float* __restrict__ b2,
     const float* __restrict__ k3, const float* __restrict__ rk3, const float* __restrict__ b3,
     const float* __restrict__ Wd, const float* __restrict__ bd,
     float* __restrict__ out)
{
  __shared__ __align__(16) __bf16 x_lds[BT * 32];        // padded K: 23 -> 32
  __shared__ __align__(16) __bf16 h0_lds[2][BT * 64];    // double-buffered
  __shared__ __align__(16) __bf16 h1_lds[2][BT * 32];
  __shared__ __align__(16) __bf16 h2_lds[2][BT * 32];
  __shared__ __align__(16) __bf16 h3_lds[2][BT * 32];
  __shared__ __align__(16) float h3f[BT * 32];

  const int tid  = threadIdx.x;
  const int lane = tid & 63;
  const int w    = tid >> 6;        // wave 0..3
  const int col  = lane & 15;       // C col / B n / A m index
  const int kb   = (lane >> 4) * 8; // A/B k base within a k-tile
  const int rowq = (lane >> 4) * 4; // C row base (batch)
  const long bbase = (long)blockIdx.x * BT;

  // ---------------- weight fragments (registers, loaded once) --------------
  // L0: all 4 waves; u=64, gates at cols [0,64), [64,128), [128,192).
  const int u0 = 16 * w;
  bf16x8 w0xz  = bfragW(k0, 23, 192,       u0 + col, kb);
  bf16x8 w0xr  = bfragW(k0, 23, 192,  64 + u0 + col, kb);
  bf16x8 w0xh  = bfragW(k0, 23, 192, 128 + u0 + col, kb);
  bf16x8 w0hz0 = bfragW(rk0, 64, 192,       u0 + col, kb);
  bf16x8 w0hz1 = bfragW(rk0, 64, 192,       u0 + col, 32 + kb);
  bf16x8 w0hr0 = bfragW(rk0, 64, 192,  64 + u0 + col, kb);
  bf16x8 w0hr1 = bfragW(rk0, 64, 192,  64 + u0 + col, 32 + kb);
  bf16x8 w0hh0 = bfragW(rk0, 64, 192, 128 + u0 + col, kb);
  bf16x8 w0hh1 = bfragW(rk0, 64, 192, 128 + u0 + col, 32 + kb);
  float bias0z  = b0[u0 + col] + b0[192 + u0 + col];
  float bias0r  = b0[64 + u0 + col] + b0[192 + 64 + u0 + col];
  float bias0xh = b0[128 + u0 + col];
  float bias0hh = b0[192 + 128 + u0 + col];

  // L1: waves 0,1; u=32, input = h0 (K=64).
  bf16x8 w1xz0, w1xz1, w1xr0, w1xr1, w1xh0, w1xh1, w1hz, w1hr, w1hh;
  float bias1z = 0, bias1r = 0, bias1xh = 0, bias1hh = 0;
  if (w < 2) {
    const int u1 = 16 * w;
    w1xz0 = bfragW(k1, 64, 96,      u1 + col, kb);
    w1xz1 = bfragW(k1, 64, 96,      u1 + col, 32 + kb);
    w1xr0 = bfragW(k1, 64, 96, 32 + u1 + col, kb);
    w1xr1 = bfragW(k1, 64, 96, 32 + u1 + col, 32 + kb);
    w1xh0 = bfragW(k1, 64, 96, 64 + u1 + col, kb);
    w1xh1 = bfragW(k1, 64, 96, 64 + u1 + col, 32 + kb);
    w1hz  = bfragW(rk1, 32, 96,      u1 + col, kb);
    w1hr  = bfragW(rk1, 32, 96, 32 + u1 + col, kb);
    w1hh  = bfragW(rk1, 32, 96, 64 + u1 + col, kb);
    bias1z  = b1[u1 + col] + b1[96 + u1 + col];
    bias1r  = b1[32 + u1 + col] + b1[96 + 32 + u1 + col];
    bias1xh = b1[64 + u1 + col];
    bias1hh = b1[96 + 64 + u1 + col];
  }

  // L2 + L3: waves 2,3; u=32, inputs K=32.
  bf16x8 w2xz, w2xr, w2xh, w2hz, w2hr, w2hh;
  bf16x8 w3xz, w3xr, w3xh, w3hz, w3hr, w3hh;
  float bias2z = 0, bias2r = 0, bias2xh = 0, bias2hh = 0;
  float bias3z = 0, bias3r = 0, bias3xh = 0, bias3hh = 0;
  if (w >= 2) {
    const int u2 = 16 * (w - 2);
    w2xz = bfragW(k2, 32, 96,      u2 + col, kb);
    w2xr = bfragW(k2, 32, 96, 32 + u2 + col, kb);
    w2xh = bfragW(k2, 32, 96, 64 + u2 + col, kb);
    w2hz = bfragW(rk2, 32, 96,      u2 + col, kb);
    w2hr = bfragW(rk2, 32, 96, 32 + u2 + col, kb);
    w2hh = bfragW(rk2, 32, 96, 64 + u2 + col, kb);
    bias2z  = b2[u2 + col] + b2[96 + u2 + col];
    bias2r  = b2[32 + u2 + col] + b2[96 + 32 + u2 + col];
    bias2xh = b2[64 + u2 + col];
    bias2hh = b2[96 + 64 + u2 + col];
    w3xz = bfragW(k3, 32, 96,      u2 + col, kb);
    w3xr = bfragW(k3, 32, 96, 32 + u2 + col, kb);
    w3xh = bfragW(k3, 32, 96, 64 + u2 + col, kb);
    w3hz = bfragW(rk3, 32, 96,      u2 + col, kb);
    w3hr = bfragW(rk3, 32, 96, 32 + u2 + col, kb);
    w3hh = bfragW(rk3, 32, 96, 64 + u2 + col, kb);
    bias3z  = b3[u2 + col] + b3[96 + u2 + col];
    bias3r  = b3[32 + u2 + col] + b3[96 + 32 + u2 + col];
    bias3xh = b3[64 + u2 + col];
    bias3hh = b3[96 + 64 + u2 + col];
  }

  // ---------------- zero-init h state ----------------
  {
    __bf16* p0 = (__bf16*)h0_lds;
    for (int i = tid; i < 2 * BT * 64; i += 256) p0[i] = (__bf16)0.f;
    __bf16* p1 = (__bf16*)h1_lds;
    __bf16* p2 = (__bf16*)h2_lds;
    __bf16* p3 = (__bf16*)h3_lds;
    for (int i = tid; i < 2 * BT * 32; i += 256) {
      p1[i] = (__bf16)0.f; p2[i] = (__bf16)0.f; p3[i] = (__bf16)0.f;
    }
  }
  float h0r[4] = {0,0,0,0}, h1r[4] = {0,0,0,0};
  float h2r[4] = {0,0,0,0}, h3r[4] = {0,0,0,0};
  __syncthreads();

  const float* binp = inp + bbase * TT * FF;

  for (int t = 0; t < TT; ++t) {
    const int pb = t & 1;      // read buffer
    const int qb = pb ^ 1;     // write buffer

    // ---- stage x_t: [f0 | feats 2..19 | emb(4) | zero pad] -> bf16 LDS ----
#pragma unroll
    for (int rep = 0; rep < 2; ++rep) {
      int idx = tid + rep * 256;          // 512 entries = 16 batch x 32 k
      int b = idx >> 5, k = idx & 31;
      const float* rowp = binp + (b * TT + t) * FF;
      float v = 0.f;
      if (k == 0) v = rowp[0];
      else if (k <= 18) v = rowp[k + 1];
      else if (k <= 22) { int id = (int)rowp[1]; v = Wemb[id * 4 + (k - 19)]; }
      x_lds[b * 32 + k] = (__bf16)v;
    }
    __syncthreads();   // B1: x ready

    // ---- Layer 0 (all waves) ----
    {
      bf16x8 ax = afragL(x_lds, 32, col, kb);
      bf16x8 a0 = afragL(h0_lds[pb], 64, col, kb);
      bf16x8 a1 = afragL(h0_lds[pb], 64, col, 32 + kb);
      f32x4 az = {0,0,0,0}, ar = {0,0,0,0}, axh = {0,0,0,0}, ahh = {0,0,0,0};
      az  = mfma16(ax, w0xz, az);  az  = mfma16(a0, w0hz0, az);  az = mfma16(a1, w0hz1, az);
      ar  = mfma16(ax, w0xr, ar);  ar  = mfma16(a0, w0hr0, ar);  ar = mfma16(a1, w0hr1, ar);
      axh = mfma16(ax, w0xh, axh);
      ahh = mfma16(a0, w0hh0, ahh); ahh = mfma16(a1, w0hh1, ahh);
#pragma unroll
      for (int r = 0; r < 4; ++r) {
        float z  = sigm(az[r] + bias0z);
        float rg = sigm(ar[r] + bias0r);
        float hc = tanh_(axh[r] + bias0xh + rg * (ahh[r] + bias0hh));
        float hn = z * h0r[r] + (1.f - z) * hc;
        h0r[r] = hn;
        h0_lds[qb][(rowq + r) * 64 + u0 + col] = (__bf16)hn;
      }
    }
    __syncthreads();   // B2: new h0 ready

    // ---- Layer 1 (waves 0,1) ----
    if (w < 2) {
      const int u1 = 16 * w;
      bf16x8 ax0 = afragL(h0_lds[qb], 64, col, kb);
      bf16x8 ax1 = afragL(h0_lds[qb], 64, col, 32 + kb);
      bf16x8 ah  = afragL(h1_lds[pb], 32, col, kb);
      f32x4 az = {0,0,0,0}, ar = {0,0,0,0}, axh = {0,0,0,0}, ahh = {0,0,0,0};
      az  = mfma16(ax0, w1xz0, az);  az  = mfma16(ax1, w1xz1, az);  az = mfma16(ah, w1hz, az);
      ar  = mfma16(ax0, w1xr0, ar);  ar  = mfma16(ax1, w1xr1, ar);  ar = mfma16(ah, w1hr, ar);
      axh = mfma16(ax0, w1xh0, axh); axh = mfma16(ax1, w1xh1, axh);
      ahh = mfma16(ah, w1hh, ahh);
#pragma unroll
      for (int r = 0; r < 4; ++r) {
        float z  = sigm(az[r] + bias1z);
        float rg = sigm(ar[r] + bias1r);
        float hc = tanh_(axh[r] + bias1xh + rg * (ahh[r] + bias1hh));
        float hn = z * h1r[r] + (1.f - z) * hc;
        h1r[r] = hn;
        h1_lds[qb][(rowq + r) * 32 + u1 + col] = (__bf16)hn;
      }
    }
    __syncthreads();   // B3: new h1 ready

    // ---- Layer 2 (waves 2,3) ----
    if (w >= 2) {
      const int u2 = 16 * (w - 2);
      bf16x8 ax = afragL(h1_lds[qb], 32, col, kb);
      bf16x8 ah = afragL(h2_lds[pb], 32, col, kb);
      f32x4 az = {0,0,0,0}, ar = {0,0,0,0}, axh = {0,0,0,0}, ahh = {0,0,0,0};
      az  = mfma16(ax, w2xz, az);  az = mfma16(ah, w2hz, az);
      ar  = mfma16(ax, w2xr, ar);  ar = mfma16(ah, w2hr, ar);
      axh = mfma16(ax, w2xh, axh);
      ahh = mfma16(ah, w2hh, ahh);
#pragma unroll
      for (int r = 0; r < 4; ++r) {
        float z  = sigm(az[r] + bias2z);
        float rg = sigm(ar[r] + bias2r);
        float hc = tanh_(axh[r] + bias2xh + rg * (ahh[r] + bias2hh));
        float hn = z * h2r[r] + (1.f - z) * hc;
        h2r[r] = hn;
        h2_lds[qb][(rowq + r) * 32 + u2 + col] = (__bf16)hn;
      }
    }
    __syncthreads();   // B4: new h2 ready (sync waves 2<->3)

    // ---- Layer 3 (waves 2,3) ----
    if (w >= 2) {
      const int u3 = 16 * (w - 2);
      bf16x8 ax = afragL(h2_lds[qb], 32, col, kb);
      bf16x8 ah = afragL(h3_lds[pb], 32, col, kb);
      f32x4 az = {0,0,0,0}, ar = {0,0,0,0}, axh = {0,0,0,0}, ahh = {0,0,0,0};
      az  = mfma16(ax, w3xz, az);  az = mfma16(ah, w3hz, az);
      ar  = mfma16(ax, w3xr, ar);  ar = mfma16(ah, w3hr, ar);
      axh = mfma16(ax, w3xh, axh);
      ahh = mfma16(ah, w3hh, ahh);
#pragma unroll
      for (int r = 0; r < 4; ++r) {
        float z  = sigm(az[r] + bias3z);
        float rg = sigm(ar[r] + bias3r);
        float hc = tanh_(axh[r] + bias3xh + rg * (ahh[r] + bias3hh));
        float hn = z * h3r[r] + (1.f - z) * hc;
        h3r[r] = hn;
        h3_lds[qb][(rowq + r) * 32 + u3 + col] = (__bf16)hn;
      }
    }
    __syncthreads();   // B5: end of step (protects x_lds restage + h3 reads)
  }

  // ---------------- epilogue: logits + softmax ----------------
  if (w >= 2) {
    const int u3 = 16 * (w - 2);
#pragma unroll
    for (int r = 0; r < 4; ++r) h3f[(rowq + r) * 32 + u3 + col] = h3r[r];
  }
  __syncthreads();

  if (tid < BT) {
    float l0 = bd[0], l1 = bd[1];
#pragma unroll
    for (int u = 0; u < 32; ++u) {
      float h = h3f[tid * 32 + u];
      l0 = fmaf(h, Wd[2 * u], l0);
      l1 = fmaf(h, Wd[2 * u + 1], l1);
    }
    float m = fmaxf(l0, l1);
    float e0 = __expf(l0 - m), e1 = __expf(l1 - m);
    float inv = 1.f / (e0 + e1);
    out[(bbase + tid) * 2 + 0] = e0 * inv;
    out[(bbase + tid) * 2 + 1] = e1 * inv;
  }
}

extern "C" void kernel_launch(void* const* d_in, const int* in_sizes, int n_in,
                              void* d_out, int out_size, void* d_ws, size_t ws_size,
                              hipStream_t stream) {
  const float* inp  = (const float*)d_in[0];
  const float* Wemb = (const float*)d_in[1];
  const float* k0   = (const float*)d_in[2];
  const float* rk0  = (const float*)d_in[3];
  const float* b0   = (const float*)d_in[4];
  const float* k1   = (const float*)d_in[5];
  const float* rk1  = (const float*)d_in[6];
  const float* b1   = (const float*)d_in[7];
  const float* k2   = (const float*)d_in[8];
  const float* rk2  = (const float*)d_in[9];
  const float* b2   = (const float*)d_in[10];
  const float* k3   = (const float*)d_in[11];
  const float* rk3  = (const float*)d_in[12];
  const float* b3   = (const float*)d_in[13];
  const float* Wd   = (const float*)d_in[14];
  const float* bd   = (const float*)d_in[15];
  float* out = (float*)d_out;

  const int Btot = in_sizes[0] / (TT * FF);   // 4096
  dim3 grid(Btot / BT);                       // 256 blocks
  gru4<<<grid, 256, 0, stream>>>(inp, Wemb, k0, rk0, b0, k1, rk1, b1,
                                 k2, rk2, b2, k3, rk3, b3, Wd, bd, out);
}

// Round 2
// 442.836 us; speedup vs baseline: 1.7862x; 1.7862x over previous
//
#include <hip/hip_runtime.h>

// 4-layer GRU stack, B=4096, T=256. 256 persistent blocks x 256 threads,
// 16 batch rows per block (one M=16 MFMA tile), loop over time.
//
// Wavefront pipelining: at pipeline step s, wave0/1 compute L0 (time s),
// wave2 computes L1 (s-1) + L2 slice0 (s-2), wave3 computes L2 slice1 (s-2)
// + L3 (s-3). All cross-wave reads are values published the PREVIOUS step
// -> double-buffered h in LDS, ONE barrier per step.
//
// x input staged in 64-step chunks into LDS (bulk coalesced, emb gather
// amortized) -> no global traffic in the steady-state step.
//
// LDS strides padded (h0: 72, h1/h2/h3: 40 bf16) so ds_read_b128 A-frag
// reads are bank-conflict-free ((36m+4g) / (20m+4g) mod 32 uniform).

typedef __attribute__((ext_vector_type(8))) __bf16 bf16x8;
typedef __attribute__((ext_vector_type(4))) float f32x4;

#define TT 256
#define FF 20
#define BT 16
#define CH 64     // x chunk steps held in LDS (64 KB)
#define SH0 72    // h0 LDS row stride (bf16 elements), padded from 64
#define SH1 40    // h1/h2/h3 LDS row stride, padded from 32

__device__ __forceinline__ f32x4 mfma16(bf16x8 a, bf16x8 b, f32x4 c) {
  return __builtin_amdgcn_mfma_f32_16x16x32_bf16(a, b, c, 0, 0, 0);
}

// NaN-free, clamp-free: correct limits at +-inf (rcp(inf)=0).
__device__ __forceinline__ float sigm(float x) {
  return __builtin_amdgcn_rcpf(1.f + __builtin_amdgcn_exp2f(-1.44269504f * x));
}
__device__ __forceinline__ float tanh_(float x) {
  return __builtin_amdgcn_rcpf(1.f + __builtin_amdgcn_exp2f(-2.88539008f * x)) * 2.f - 1.f;
}

// B-operand fragment from global row-major W[K][N]: lane holds col n, k=kbase+j.
__device__ __forceinline__ bf16x8 bfragW(const float* W, int Kreal, int N,
                                         int ncol, int kbase) {
  bf16x8 r;
#pragma unroll
  for (int j = 0; j < 8; ++j) {
    int k = kbase + j;
    r[j] = (__bf16)(k < Kreal ? W[k * N + ncol] : 0.f);
  }
  return r;
}

// A-operand fragment from LDS row-major act[M][stride]: one ds_read_b128.
__device__ __forceinline__ bf16x8 afrag(const __bf16* base, int stride, int m,
                                        int kbase) {
  return *(const bf16x8*)(base + m * stride + kbase);
}

// Fused gate block for one 16-unit slice (4 rows per lane).
__device__ __forceinline__ void gates(f32x4 az, f32x4 ar, f32x4 axh, f32x4 ahh,
                                      float bz, float br, float bxh, float bhh,
                                      float* h, __bf16* dst, int stride, int rowq) {
#pragma unroll
  for (int r = 0; r < 4; ++r) {
    float z  = sigm(az[r] + bz);
    float rg = sigm(ar[r] + br);
    float hc = tanh_(fmaf(rg, ahh[r] + bhh, axh[r] + bxh));
    float hn = fmaf(z, h[r] - hc, hc);
    h[r] = hn;
    dst[(rowq + r) * stride] = (__bf16)hn;
  }
}

extern "C" __global__ void __launch_bounds__(256)
gru4(const float* __restrict__ inp, const float* __restrict__ Wemb,
     const float* __restrict__ k0, const float* __restrict__ rk0, const float* __restrict__ b0,
     const float* __restrict__ k1, const float* __restrict__ rk1, const float* __restrict__ b1,
     const float* __restrict__ k2, const float* __restrict__ rk2, const float* __restrict__ b2,
     const float* __restrict__ k3, const float* __restrict__ rk3, const float* __restrict__ b3,
     const float* __restrict__ Wd, const float* __restrict__ bd,
     float* __restrict__ out)
{
  __shared__ __align__(16) __bf16 x_ch[CH][BT][32];      // 64 KB
  __shared__ __align__(16) __bf16 h0_lds[2][BT * SH0];   // 4.5 KB
  __shared__ __align__(16) __bf16 h1_lds[2][BT * SH1];   // 2.5 KB
  __shared__ __align__(16) __bf16 h2_lds[2][BT * SH1];
  __shared__ __align__(16) __bf16 h3_lds[2][BT * SH1];
  __shared__ __align__(16) float h3f[BT * 32];

  const int tid  = threadIdx.x;
  const int lane = tid & 63;
  const int w    = tid >> 6;        // wave 0..3
  const int col  = lane & 15;       // C col / B n / A m index
  const int kb   = (lane >> 4) * 8; // A/B k base within a k-tile
  const int rowq = (lane >> 4) * 4; // C row base (batch)
  const long bbase = (long)blockIdx.x * BT;
  const float* binp = inp + bbase * TT * FF;

  // ------------- weight fragments (registers, loaded once) -------------
  // wave0/1: L0 halves. slice sl -> units w*32 + sl*16 .. +15
  bf16x8 w0xz[2], w0xr[2], w0xh[2];
  bf16x8 w0hz[2][2], w0hr[2][2], w0hh[2][2];
  float b0z[2], b0r[2], b0xh[2], b0hh[2];
  if (w < 2) {
#pragma unroll
    for (int sl = 0; sl < 2; ++sl) {
      int u = w * 32 + sl * 16 + col;
      w0xz[sl] = bfragW(k0, 23, 192, u, kb);
      w0xr[sl] = bfragW(k0, 23, 192, 64 + u, kb);
      w0xh[sl] = bfragW(k0, 23, 192, 128 + u, kb);
      w0hz[sl][0] = bfragW(rk0, 64, 192, u, kb);
      w0hz[sl][1] = bfragW(rk0, 64, 192, u, 32 + kb);
      w0hr[sl][0] = bfragW(rk0, 64, 192, 64 + u, kb);
      w0hr[sl][1] = bfragW(rk0, 64, 192, 64 + u, 32 + kb);
      w0hh[sl][0] = bfragW(rk0, 64, 192, 128 + u, kb);
      w0hh[sl][1] = bfragW(rk0, 64, 192, 128 + u, 32 + kb);
      b0z[sl]  = b0[u] + b0[192 + u];
      b0r[sl]  = b0[64 + u] + b0[192 + 64 + u];
      b0xh[sl] = b0[128 + u];
      b0hh[sl] = b0[192 + 128 + u];
    }
  }

  // wave2: L1 (both slices) + L2 slice0 (units 0..15)
  bf16x8 w1xz[2][2], w1xr[2][2], w1xh[2][2], w1hz[2], w1hr[2], w1hh[2];
  float b1z[2], b1r[2], b1xh[2], b1hh[2];
  bf16x8 w2xz_a, w2xr_a, w2xh_a, w2hz_a, w2hr_a, w2hh_a;
  float b2z_a = 0, b2r_a = 0, b2xh_a = 0, b2hh_a = 0;
  if (w == 2) {
#pragma unroll
    for (int sl = 0; sl < 2; ++sl) {
      int u = sl * 16 + col;
      w1xz[sl][0] = bfragW(k1, 64, 96, u, kb);
      w1xz[sl][1] = bfragW(k1, 64, 96, u, 32 + kb);
      w1xr[sl][0] = bfragW(k1, 64, 96, 32 + u, kb);
      w1xr[sl][1] = bfragW(k1, 64, 96, 32 + u, 32 + kb);
      w1xh[sl][0] = bfragW(k1, 64, 96, 64 + u, kb);
      w1xh[sl][1] = bfragW(k1, 64, 96, 64 + u, 32 + kb);
      w1hz[sl] = bfragW(rk1, 32, 96, u, kb);
      w1hr[sl] = bfragW(rk1, 32, 96, 32 + u, kb);
      w1hh[sl] = bfragW(rk1, 32, 96, 64 + u, kb);
      b1z[sl]  = b1[u] + b1[96 + u];
      b1r[sl]  = b1[32 + u] + b1[96 + 32 + u];
      b1xh[sl] = b1[64 + u];
      b1hh[sl] = b1[96 + 64 + u];
    }
    int u = col;  // L2 slice0
    w2xz_a = bfragW(k2, 32, 96, u, kb);
    w2xr_a = bfragW(k2, 32, 96, 32 + u, kb);
    w2xh_a = bfragW(k2, 32, 96, 64 + u, kb);
    w2hz_a = bfragW(rk2, 32, 96, u, kb);
    w2hr_a = bfragW(rk2, 32, 96, 32 + u, kb);
    w2hh_a = bfragW(rk2, 32, 96, 64 + u, kb);
    b2z_a  = b2[u] + b2[96 + u];
    b2r_a  = b2[32 + u] + b2[96 + 32 + u];
    b2xh_a = b2[64 + u];
    b2hh_a = b2[96 + 64 + u];
  }

  // wave3: L2 slice1 (units 16..31) + L3 (both slices)
  bf16x8 w2xz_b, w2xr_b, w2xh_b, w2hz_b, w2hr_b, w2hh_b;
  float b2z_b = 0, b2r_b = 0, b2xh_b = 0, b2hh_b = 0;
  bf16x8 w3xz[2], w3xr[2], w3xh[2], w3hz[2], w3hr[2], w3hh[2];
  float b3z[2], b3r[2], b3xh[2], b3hh[2];
  if (w == 3) {
    int u = 16 + col;  // L2 slice1
    w2xz_b = bfragW(k2, 32, 96, u, kb);
    w2xr_b = bfragW(k2, 32, 96, 32 + u, kb);
    w2xh_b = bfragW(k2, 32, 96, 64 + u, kb);
    w2hz_b = bfragW(rk2, 32, 96, u, kb);
    w2hr_b = bfragW(rk2, 32, 96, 32 + u, kb);
    w2hh_b = bfragW(rk2, 32, 96, 64 + u, kb);
    b2z_b  = b2[u] + b2[96 + u];
    b2r_b  = b2[32 + u] + b2[96 + 32 + u];
    b2xh_b = b2[64 + u];
    b2hh_b = b2[96 + 64 + u];
#pragma unroll
    for (int sl = 0; sl < 2; ++sl) {
      int v = sl * 16 + col;
      w3xz[sl] = bfragW(k3, 32, 96, v, kb);
      w3xr[sl] = bfragW(k3, 32, 96, 32 + v, kb);
      w3xh[sl] = bfragW(k3, 32, 96, 64 + v, kb);
      w3hz[sl] = bfragW(rk3, 32, 96, v, kb);
      w3hr[sl] = bfragW(rk3, 32, 96, 32 + v, kb);
      w3hh[sl] = bfragW(rk3, 32, 96, 64 + v, kb);
      b3z[sl]  = b3[v] + b3[96 + v];
      b3r[sl]  = b3[32 + v] + b3[96 + 32 + v];
      b3xh[sl] = b3[64 + v];
      b3hh[sl] = b3[96 + 64 + v];
    }
  }

  // ------------- zero-init h state -------------
  {
    __bf16* p0 = (__bf16*)h0_lds;
    for (int i = tid; i < 2 * BT * SH0; i += 256) p0[i] = (__bf16)0.f;
    __bf16* p1 = (__bf16*)h1_lds;
    __bf16* p2 = (__bf16*)h2_lds;
    __bf16* p3 = (__bf16*)h3_lds;
    for (int i = tid; i < 2 * BT * SH1; i += 256) {
      p1[i] = (__bf16)0.f; p2[i] = (__bf16)0.f; p3[i] = (__bf16)0.f;
    }
  }
  float h0r[2][4] = {{0,0,0,0},{0,0,0,0}};
  float h1r[2][4] = {{0,0,0,0},{0,0,0,0}};
  float h2ra[4] = {0,0,0,0}, h2rb[4] = {0,0,0,0};
  float h3r[2][4] = {{0,0,0,0},{0,0,0,0}};
  __syncthreads();

  for (int s = 0; s < TT + 3; ++s) {
    // ---- bulk x staging every CH steps (all threads, coalesced) ----
    if ((s & (CH - 1)) == 0 && s < TT) {
      const int row = tid >> 4;
      const int tg  = (tid & 15) * 4;
      const float* rp = binp + ((long)row * TT + s + tg) * FF;
#pragma unroll
      for (int tt = 0; tt < 4; ++tt) {
        const float* p = rp + tt * FF;
        float4 v0 = *(const float4*)(p);
        float4 v1 = *(const float4*)(p + 4);
        float4 v2 = *(const float4*)(p + 8);
        float4 v3 = *(const float4*)(p + 12);
        float4 v4 = *(const float4*)(p + 16);
        float4 e  = *(const float4*)(Wemb + 4 * (int)v0.y);
        __bf16* d = &x_ch[tg + tt][row][0];
        bf16x8 q0 = {(__bf16)v0.x, (__bf16)v0.z, (__bf16)v0.w, (__bf16)v1.x,
                     (__bf16)v1.y, (__bf16)v1.z, (__bf16)v1.w, (__bf16)v2.x};
        bf16x8 q1 = {(__bf16)v2.y, (__bf16)v2.z, (__bf16)v2.w, (__bf16)v3.x,
                     (__bf16)v3.y, (__bf16)v3.z, (__bf16)v3.w, (__bf16)v4.x};
        bf16x8 q2 = {(__bf16)v4.y, (__bf16)v4.z, (__bf16)v4.w, (__bf16)e.x,
                     (__bf16)e.y,  (__bf16)e.z,  (__bf16)e.w,  (__bf16)0.f};
        bf16x8 q3 = {(__bf16)0.f, (__bf16)0.f, (__bf16)0.f, (__bf16)0.f,
                     (__bf16)0.f, (__bf16)0.f, (__bf16)0.f, (__bf16)0.f};
        *(bf16x8*)(d)      = q0;
        *(bf16x8*)(d + 8)  = q1;
        *(bf16x8*)(d + 16) = q2;
        *(bf16x8*)(d + 24) = q3;
      }
      __syncthreads();
    }

    const int pb = (s + 1) & 1;  // read buffer  ((s-1)&1)
    const int qb = s & 1;        // write buffer

    // ---- wave0/1: L0, time t0 = s ----
    if (w < 2 && s < TT) {
      const int tl = s & (CH - 1);
      bf16x8 ax = afrag(&x_ch[tl][0][0], 32, col, kb);
      bf16x8 a0 = afrag(h0_lds[pb], SH0, col, kb);
      bf16x8 a1 = afrag(h0_lds[pb], SH0, col, 32 + kb);
#pragma unroll
      for (int sl = 0; sl < 2; ++sl) {
        f32x4 az = {0,0,0,0}, ar = {0,0,0,0}, axh = {0,0,0,0}, ahh = {0,0,0,0};
        az = mfma16(ax, w0xz[sl], az);
        az = mfma16(a0, w0hz[sl][0], az);
        az = mfma16(a1, w0hz[sl][1], az);
        ar = mfma16(ax, w0xr[sl], ar);
        ar = mfma16(a0, w0hr[sl][0], ar);
        ar = mfma16(a1, w0hr[sl][1], ar);
        axh = mfma16(ax, w0xh[sl], axh);
        ahh = mfma16(a0, w0hh[sl][0], ahh);
        ahh = mfma16(a1, w0hh[sl][1], ahh);
        gates(az, ar, axh, ahh, b0z[sl], b0r[sl], b0xh[sl], b0hh[sl],
              h0r[sl], &h0_lds[qb][w * 32 + sl * 16 + col], SH0, rowq);
      }
    }

    // ---- wave2: L1 (t = s-1), then L2 slice0 (t = s-2) ----
    if (w == 2) {
      if (s >= 1 && s <= TT) {
        bf16x8 ax0 = afrag(h0_lds[pb], SH0, col, kb);
        bf16x8 ax1 = afrag(h0_lds[pb], SH0, col, 32 + kb);
        bf16x8 ah  = afrag(h1_lds[pb], SH1, col, kb);
#pragma unroll
        for (int sl = 0; sl < 2; ++sl) {
          f32x4 az = {0,0,0,0}, ar = {0,0,0,0}, axh = {0,0,0,0}, ahh = {0,0,0,0};
          az = mfma16(ax0, w1xz[sl][0], az);
          az = mfma16(ax1, w1xz[sl][1], az);
          az = mfma16(ah,  w1hz[sl],    az);
          ar = mfma16(ax0, w1xr[sl][0], ar);
          ar = mfma16(ax1, w1xr[sl][1], ar);
          ar = mfma16(ah,  w1hr[sl],    ar);
          axh = mfma16(ax0, w1xh[sl][0], axh);
          axh = mfma16(ax1, w1xh[sl][1], axh);
          ahh = mfma16(ah,  w1hh[sl],    ahh);
          gates(az, ar, axh, ahh, b1z[sl], b1r[sl], b1xh[sl], b1hh[sl],
                h1r[sl], &h1_lds[qb][sl * 16 + col], SH1, rowq);
        }
      }
      if (s >= 2 && s <= TT + 1) {
        bf16x8 ax = afrag(h1_lds[pb], SH1, col, kb);   // h1[s-2]
        bf16x8 ah = afrag(h2_lds[pb], SH1, col, kb);   // h2[s-3]
        f32x4 az = {0,0,0,0}, ar = {0,0,0,0}, axh = {0,0,0,0}, ahh = {0,0,0,0};
        az = mfma16(ax, w2xz_a, az);  az = mfma16(ah, w2hz_a, az);
        ar = mfma16(ax, w2xr_a, ar);  ar = mfma16(ah, w2hr_a, ar);
        axh = mfma16(ax, w2xh_a, axh);
        ahh = mfma16(ah, w2hh_a, ahh);
        gates(az, ar, axh, ahh, b2z_a, b2r_a, b2xh_a, b2hh_a,
              h2ra, &h2_lds[qb][col], SH1, rowq);
      }
    }

    // ---- wave3: L2 slice1 (t = s-2), then L3 (t = s-3) ----
    if (w == 3) {
      if (s >= 2 && s <= TT + 1) {
        bf16x8 ax = afrag(h1_lds[pb], SH1, col, kb);
        bf16x8 ah = afrag(h2_lds[pb], SH1, col, kb);
        f32x4 az = {0,0,0,0}, ar = {0,0,0,0}, axh = {0,0,0,0}, ahh = {0,0,0,0};
        az = mfma16(ax, w2xz_b, az);  az = mfma16(ah, w2hz_b, az);
        ar = mfma16(ax, w2xr_b, ar);  ar = mfma16(ah, w2hr_b, ar);
        axh = mfma16(ax, w2xh_b, axh);
        ahh = mfma16(ah, w2hh_b, ahh);
        gates(az, ar, axh, ahh, b2z_b, b2r_b, b2xh_b, b2hh_b,
              h2rb, &h2_lds[qb][16 + col], SH1, rowq);
      }
      if (s >= 3) {   // s <= TT+2 always true inside loop
        bf16x8 ax = afrag(h2_lds[pb], SH1, col, kb);   // h2[s-3]
        bf16x8 ah = afrag(h3_lds[pb], SH1, col, kb);   // h3[s-4]
#pragma unroll
        for (int sl = 0; sl < 2; ++sl) {
          f32x4 az = {0,0,0,0}, ar = {0,0,0,0}, axh = {0,0,0,0}, ahh = {0,0,0,0};
          az = mfma16(ax, w3xz[sl], az);  az = mfma16(ah, w3hz[sl], az);
          ar = mfma16(ax, w3xr[sl], ar);  ar = mfma16(ah, w3hr[sl], ar);
          axh = mfma16(ax, w3xh[sl], axh);
          ahh = mfma16(ah, w3hh[sl], ahh);
          gates(az, ar, axh, ahh, b3z[sl], b3r[sl], b3xh[sl], b3hh[sl],
                h3r[sl], &h3_lds[qb][sl * 16 + col], SH1, rowq);
        }
      }
    }

    __syncthreads();   // single per-step barrier
  }

  // ------------- epilogue: logits + softmax -------------
  if (w == 3) {
#pragma unroll
    for (int sl = 0; sl < 2; ++sl)
#pragma unroll
      for (int r = 0; r < 4; ++r)
        h3f[(rowq + r) * 32 + sl * 16 + col] = h3r[sl][r];
  }
  __syncthreads();

  if (tid < BT) {
    float l0 = bd[0], l1 = bd[1];
#pragma unroll
    for (int u = 0; u < 32; ++u) {
      float h = h3f[tid * 32 + u];
      l0 = fmaf(h, Wd[2 * u], l0);
      l1 = fmaf(h, Wd[2 * u + 1], l1);
    }
    float m = fmaxf(l0, l1);
    float e0 = __builtin_amdgcn_exp2f((l0 - m) * 1.44269504f);
    float e1 = __builtin_amdgcn_exp2f((l1 - m) * 1.44269504f);
    float inv = 1.f / (e0 + e1);
    out[(bbase + tid) * 2 + 0] = e0 * inv;
    out[(bbase + tid) * 2 + 1] = e1 * inv;
  }
}

extern "C" void kernel_launch(void* const* d_in, const int* in_sizes, int n_in,
                              void* d_out, int out_size, void* d_ws, size_t ws_size,
                              hipStream_t stream) {
  const float* inp  = (const float*)d_in[0];
  const float* Wemb = (const float*)d_in[1];
  const float* k0   = (const float*)d_in[2];
  const float* rk0  = (const float*)d_in[3];
  const float* b0   = (const float*)d_in[4];
  const float* k1   = (const float*)d_in[5];
  const float* rk1  = (const float*)d_in[6];
  const float* b1   = (const float*)d_in[7];
  const float* k2   = (const float*)d_in[8];
  const float* rk2  = (const float*)d_in[9];
  const float* b2   = (const float*)d_in[10];
  const float* k3   = (const float*)d_in[11];
  const float* rk3  = (const float*)d_in[12];
  const float* b3   = (const float*)d_in[13];
  const float* Wd   = (const float*)d_in[14];
  const float* bd   = (const float*)d_in[15];
  float* out = (float*)d_out;

  const int Btot = in_sizes[0] / (TT * FF);   // 4096
  dim3 grid(Btot / BT);                       // 256 blocks
  gru4<<<grid, 256, 0, stream>>>(inp, Wemb, k0, rk0, b0, k1, rk1, b1,
                                 k2, rk2, b2, k3, rk3, b3, Wd, bd, out);
}

// Round 3
// 365.623 us; speedup vs baseline: 2.1634x; 1.2112x over previous
//
#include <hip/hip_runtime.h>

// 4-layer GRU stack, B=4096, T=256. 256 persistent blocks x 512 threads
// (8 waves), 16 batch rows per block (one M=16 MFMA tile), loop over time.
//
// Wavefront pipelining across layers, one 16-unit gate slice per wave:
//   w0..w3: L0 slices 0..3   (time t = s)
//   w4,w5 : L1 slices 0,1    (t = s-1)
//   w6,w7 : L2 slice + L3 slice (t = s-2 / s-3)
// All cross-wave reads are values published the PREVIOUS step ->
// double-buffered h in LDS, ONE barrier per step. 8 waves = 2 per SIMD,
// so each SIMD interleaves two waves and hides gate-chain/LDS latency.
//
// x input staged in 64-step chunks into LDS (bulk coalesced, emb gather
// amortized). Gate biases are folded into the MFMA accumulator init.
// LDS strides padded: h0 rows 72, h1/h2/h3 rows 40, x t-plane 648 bf16
// -> all hot-loop ds_read_b128 are bank-conflict-free.

typedef __attribute__((ext_vector_type(8))) __bf16 bf16x8;
typedef __attribute__((ext_vector_type(4))) float f32x4;

#define TT 256
#define FF 20
#define BT 16
#define CH 64      // x chunk steps held in LDS
#define SH0 72     // h0 LDS row stride (bf16), padded from 64
#define SH1 40     // h1/h2/h3 LDS row stride, padded from 32
#define XSTR 648   // x_ch t-plane stride (bf16): 16*40 + 8 pad

__device__ __forceinline__ f32x4 mfma16(bf16x8 a, bf16x8 b, f32x4 c) {
  return __builtin_amdgcn_mfma_f32_16x16x32_bf16(a, b, c, 0, 0, 0);
}

// NaN-free, clamp-free: correct limits at +-inf (rcp(inf)=0).
__device__ __forceinline__ float sigm(float x) {
  return __builtin_amdgcn_rcpf(1.f + __builtin_amdgcn_exp2f(-1.44269504f * x));
}
__device__ __forceinline__ float tanh_(float x) {
  return __builtin_amdgcn_rcpf(1.f + __builtin_amdgcn_exp2f(-2.88539008f * x)) * 2.f - 1.f;
}

// B-operand fragment from global row-major W[K][N]: lane holds col n, k=kbase+j.
__device__ __forceinline__ bf16x8 bfragW(const float* W, int Kreal, int N,
                                         int ncol, int kbase) {
  bf16x8 r;
#pragma unroll
  for (int j = 0; j < 8; ++j) {
    int k = kbase + j;
    r[j] = (__bf16)(k < Kreal ? W[k * N + ncol] : 0.f);
  }
  return r;
}

// A-operand fragment from LDS row-major act[M][stride]: one ds_read_b128.
__device__ __forceinline__ bf16x8 afrag(const __bf16* base, int stride, int m,
                                        int kbase) {
  return *(const bf16x8*)(base + m * stride + kbase);
}

// Fused gate block for one 16-unit slice (biases pre-folded into accums).
__device__ __forceinline__ void gates(f32x4 az, f32x4 ar, f32x4 axh, f32x4 ahh,
                                      float* h, __bf16* dst, int stride, int rowq) {
#pragma unroll
  for (int r = 0; r < 4; ++r) {
    float z  = sigm(az[r]);
    float rg = sigm(ar[r]);
    float hc = tanh_(fmaf(rg, ahh[r], axh[r]));
    float hn = fmaf(z, h[r] - hc, hc);
    h[r] = hn;
    dst[(rowq + r) * stride] = (__bf16)hn;
  }
}

extern "C" __global__ void __launch_bounds__(512, 2)
gru4(const float* __restrict__ inp, const float* __restrict__ Wemb,
     const float* __restrict__ k0, const float* __restrict__ rk0, const float* __restrict__ b0,
     const float* __restrict__ k1, const float* __restrict__ rk1, const float* __restrict__ b1,
     const float* __restrict__ k2, const float* __restrict__ rk2, const float* __restrict__ b2,
     const float* __restrict__ k3, const float* __restrict__ rk3, const float* __restrict__ b3,
     const float* __restrict__ Wd, const float* __restrict__ bd,
     float* __restrict__ out)
{
  __shared__ __align__(16) __bf16 x_ch[CH * XSTR];       // ~83 KB
  __shared__ __align__(16) __bf16 h0_lds[2][BT * SH0];
  __shared__ __align__(16) __bf16 h1_lds[2][BT * SH1];
  __shared__ __align__(16) __bf16 h2_lds[2][BT * SH1];
  __shared__ __align__(16) __bf16 h3_lds[2][BT * SH1];
  __shared__ __align__(16) float h3f[BT * 32];

  const int tid  = threadIdx.x;
  const int lane = tid & 63;
  const int w    = tid >> 6;        // wave 0..7
  const int col  = lane & 15;       // C col / B n / A m index
  const int kb   = (lane >> 4) * 8; // A/B k base within a k-tile
  const int rowq = (lane >> 4) * 4; // C row base (batch)
  const long bbase = (long)blockIdx.x * BT;
  const float* binp = inp + bbase * TT * FF;

  // ------------- weight fragments (registers, loaded once) -------------
  // w0..w3: L0 slice w (units w*16..+15)
  bf16x8 z0x, r0x, g0x, z0h0, z0h1, r0h0, r0h1, g0h0, g0h1;
  float bz0 = 0, br0 = 0, bxh0 = 0, bhh0 = 0;
  if (w < 4) {
    int u = w * 16 + col;
    z0x  = bfragW(k0, 23, 192, u, kb);
    r0x  = bfragW(k0, 23, 192, 64 + u, kb);
    g0x  = bfragW(k0, 23, 192, 128 + u, kb);
    z0h0 = bfragW(rk0, 64, 192, u, kb);
    z0h1 = bfragW(rk0, 64, 192, u, 32 + kb);
    r0h0 = bfragW(rk0, 64, 192, 64 + u, kb);
    r0h1 = bfragW(rk0, 64, 192, 64 + u, 32 + kb);
    g0h0 = bfragW(rk0, 64, 192, 128 + u, kb);
    g0h1 = bfragW(rk0, 64, 192, 128 + u, 32 + kb);
    bz0  = b0[u] + b0[192 + u];
    br0  = b0[64 + u] + b0[192 + 64 + u];
    bxh0 = b0[128 + u];
    bhh0 = b0[192 + 128 + u];
  }

  // w4,w5: L1 slice (w-4)
  bf16x8 z1x0, z1x1, r1x0, r1x1, g1x0, g1x1, z1h, r1h, g1h;
  float bz1 = 0, br1 = 0, bxh1 = 0, bhh1 = 0;
  if (w == 4 || w == 5) {
    int u = (w - 4) * 16 + col;
    z1x0 = bfragW(k1, 64, 96, u, kb);
    z1x1 = bfragW(k1, 64, 96, u, 32 + kb);
    r1x0 = bfragW(k1, 64, 96, 32 + u, kb);
    r1x1 = bfragW(k1, 64, 96, 32 + u, 32 + kb);
    g1x0 = bfragW(k1, 64, 96, 64 + u, kb);
    g1x1 = bfragW(k1, 64, 96, 64 + u, 32 + kb);
    z1h  = bfragW(rk1, 32, 96, u, kb);
    r1h  = bfragW(rk1, 32, 96, 32 + u, kb);
    g1h  = bfragW(rk1, 32, 96, 64 + u, kb);
    bz1  = b1[u] + b1[96 + u];
    br1  = b1[32 + u] + b1[96 + 32 + u];
    bxh1 = b1[64 + u];
    bhh1 = b1[96 + 64 + u];
  }

  // w6,w7: L2 slice (w-6) + L3 slice (w-6)
  bf16x8 z2x, r2x, g2x, z2h, r2h, g2h;
  bf16x8 z3x, r3x, g3x, z3h, r3h, g3h;
  float bz2 = 0, br2 = 0, bxh2 = 0, bhh2 = 0;
  float bz3 = 0, br3 = 0, bxh3 = 0, bhh3 = 0;
  if (w >= 6) {
    int u = (w - 6) * 16 + col;
    z2x = bfragW(k2, 32, 96, u, kb);
    r2x = bfragW(k2, 32, 96, 32 + u, kb);
    g2x = bfragW(k2, 32, 96, 64 + u, kb);
    z2h = bfragW(rk2, 32, 96, u, kb);
    r2h = bfragW(rk2, 32, 96, 32 + u, kb);
    g2h = bfragW(rk2, 32, 96, 64 + u, kb);
    bz2  = b2[u] + b2[96 + u];
    br2  = b2[32 + u] + b2[96 + 32 + u];
    bxh2 = b2[64 + u];
    bhh2 = b2[96 + 64 + u];
    z3x = bfragW(k3, 32, 96, u, kb);
    r3x = bfragW(k3, 32, 96, 32 + u, kb);
    g3x = bfragW(k3, 32, 96, 64 + u, kb);
    z3h = bfragW(rk3, 32, 96, u, kb);
    r3h = bfragW(rk3, 32, 96, 32 + u, kb);
    g3h = bfragW(rk3, 32, 96, 64 + u, kb);
    bz3  = b3[u] + b3[96 + u];
    br3  = b3[32 + u] + b3[96 + 32 + u];
    bxh3 = b3[64 + u];
    bhh3 = b3[96 + 64 + u];
  }

  // ------------- zero-init h state -------------
  {
    __bf16* p0 = (__bf16*)h0_lds;
    for (int i = tid; i < 2 * BT * SH0; i += 512) p0[i] = (__bf16)0.f;
    __bf16* p1 = (__bf16*)h1_lds;
    __bf16* p2 = (__bf16*)h2_lds;
    __bf16* p3 = (__bf16*)h3_lds;
    for (int i = tid; i < 2 * BT * SH1; i += 512) {
      p1[i] = (__bf16)0.f; p2[i] = (__bf16)0.f; p3[i] = (__bf16)0.f;
    }
  }
  float h0r[4] = {0,0,0,0}, h1r[4] = {0,0,0,0};
  float h2r[4] = {0,0,0,0}, h3r[4] = {0,0,0,0};
  __syncthreads();

  for (int s = 0; s < TT + 3; ++s) {
    // ---- bulk x staging every CH steps (all 512 threads, coalesced) ----
    if ((s & (CH - 1)) == 0 && s < TT) {
      const int row = tid >> 5;          // 0..15
      const int tg  = (tid & 31) * 2;    // 0,2,..,62
      const float* rp = binp + ((long)row * TT + s + tg) * FF;
#pragma unroll
      for (int tt = 0; tt < 2; ++tt) {
        const float* p = rp + tt * FF;
        float4 v0 = *(const float4*)(p);
        float4 v1 = *(const float4*)(p + 4);
        float4 v2 = *(const float4*)(p + 8);
        float4 v3 = *(const float4*)(p + 12);
        float4 v4 = *(const float4*)(p + 16);
        float4 e  = *(const float4*)(Wemb + 4 * (int)v0.y);
        __bf16* d = &x_ch[(tg + tt) * XSTR + row * 40];
        bf16x8 q0 = {(__bf16)v0.x, (__bf16)v0.z, (__bf16)v0.w, (__bf16)v1.x,
                     (__bf16)v1.y, (__bf16)v1.z, (__bf16)v1.w, (__bf16)v2.x};
        bf16x8 q1 = {(__bf16)v2.y, (__bf16)v2.z, (__bf16)v2.w, (__bf16)v3.x,
                     (__bf16)v3.y, (__bf16)v3.z, (__bf16)v3.w, (__bf16)v4.x};
        bf16x8 q2 = {(__bf16)v4.y, (__bf16)v4.z, (__bf16)v4.w, (__bf16)e.x,
                     (__bf16)e.y,  (__bf16)e.z,  (__bf16)e.w,  (__bf16)0.f};
        bf16x8 q3 = {(__bf16)0.f, (__bf16)0.f, (__bf16)0.f, (__bf16)0.f,
                     (__bf16)0.f, (__bf16)0.f, (__bf16)0.f, (__bf16)0.f};
        *(bf16x8*)(d)      = q0;
        *(bf16x8*)(d + 8)  = q1;
        *(bf16x8*)(d + 16) = q2;
        *(bf16x8*)(d + 24) = q3;
      }
      __syncthreads();
    }

    const int pb = (s + 1) & 1;  // read buffer
    const int qb = s & 1;        // write buffer

    if (w < 4) {
      // ---- L0 slice w, t = s ----
      if (s < TT) {
        const int tl = s & (CH - 1);
        bf16x8 ax = *(const bf16x8*)(&x_ch[tl * XSTR + col * 40 + kb]);
        bf16x8 a0 = afrag(h0_lds[pb], SH0, col, kb);
        bf16x8 a1 = afrag(h0_lds[pb], SH0, col, 32 + kb);
        f32x4 az  = {bz0, bz0, bz0, bz0};
        f32x4 ar  = {br0, br0, br0, br0};
        f32x4 axh = {bxh0, bxh0, bxh0, bxh0};
        f32x4 ahh = {bhh0, bhh0, bhh0, bhh0};
        az  = mfma16(ax, z0x, az);  az  = mfma16(a0, z0h0, az);  az = mfma16(a1, z0h1, az);
        ar  = mfma16(ax, r0x, ar);  ar  = mfma16(a0, r0h0, ar);  ar = mfma16(a1, r0h1, ar);
        axh = mfma16(ax, g0x, axh);
        ahh = mfma16(a0, g0h0, ahh); ahh = mfma16(a1, g0h1, ahh);
        gates(az, ar, axh, ahh, h0r, &h0_lds[qb][w * 16 + col], SH0, rowq);
      }
    } else if (w < 6) {
      // ---- L1 slice (w-4), t = s-1 ----
      if (s >= 1 && s <= TT) {
        bf16x8 ax0 = afrag(h0_lds[pb], SH0, col, kb);
        bf16x8 ax1 = afrag(h0_lds[pb], SH0, col, 32 + kb);
        bf16x8 ah  = afrag(h1_lds[pb], SH1, col, kb);
        f32x4 az  = {bz1, bz1, bz1, bz1};
        f32x4 ar  = {br1, br1, br1, br1};
        f32x4 axh = {bxh1, bxh1, bxh1, bxh1};
        f32x4 ahh = {bhh1, bhh1, bhh1, bhh1};
        az  = mfma16(ax0, z1x0, az);  az  = mfma16(ax1, z1x1, az);  az = mfma16(ah, z1h, az);
        ar  = mfma16(ax0, r1x0, ar);  ar  = mfma16(ax1, r1x1, ar);  ar = mfma16(ah, r1h, ar);
        axh = mfma16(ax0, g1x0, axh); axh = mfma16(ax1, g1x1, axh);
        ahh = mfma16(ah, g1h, ahh);
        gates(az, ar, axh, ahh, h1r, &h1_lds[qb][(w - 4) * 16 + col], SH1, rowq);
      }
    } else {
      // hoist all previous-buffer reads so they issue together
      bf16x8 a1 = afrag(h1_lds[pb], SH1, col, kb);   // h1[s-2]
      bf16x8 a2 = afrag(h2_lds[pb], SH1, col, kb);   // h2[s-3]
      bf16x8 a3 = afrag(h3_lds[pb], SH1, col, kb);   // h3[s-4]
      // ---- L2 slice (w-6), t = s-2 ----
      if (s >= 2 && s <= TT + 1) {
        f32x4 az  = {bz2, bz2, bz2, bz2};
        f32x4 ar  = {br2, br2, br2, br2};
        f32x4 axh = {bxh2, bxh2, bxh2, bxh2};
        f32x4 ahh = {bhh2, bhh2, bhh2, bhh2};
        az  = mfma16(a1, z2x, az);  az = mfma16(a2, z2h, az);
        ar  = mfma16(a1, r2x, ar);  ar = mfma16(a2, r2h, ar);
        axh = mfma16(a1, g2x, axh);
        ahh = mfma16(a2, g2h, ahh);
        gates(az, ar, axh, ahh, h2r, &h2_lds[qb][(w - 6) * 16 + col], SH1, rowq);
      }
      // ---- L3 slice (w-6), t = s-3 ----
      if (s >= 3) {
        f32x4 az  = {bz3, bz3, bz3, bz3};
        f32x4 ar  = {br3, br3, br3, br3};
        f32x4 axh = {bxh3, bxh3, bxh3, bxh3};
        f32x4 ahh = {bhh3, bhh3, bhh3, bhh3};
        az  = mfma16(a2, z3x, az);  az = mfma16(a3, z3h, az);
        ar  = mfma16(a2, r3x, ar);  ar = mfma16(a3, r3h, ar);
        axh = mfma16(a2, g3x, axh);
        ahh = mfma16(a3, g3h, ahh);
        gates(az, ar, axh, ahh, h3r, &h3_lds[qb][(w - 6) * 16 + col], SH1, rowq);
      }
    }

    __syncthreads();   // single per-step barrier
  }

  // ------------- epilogue: logits + softmax -------------
  if (w >= 6) {
#pragma unroll
    for (int r = 0; r < 4; ++r)
      h3f[(rowq + r) * 32 + (w - 6) * 16 + col] = h3r[r];
  }
  __syncthreads();

  if (tid < BT) {
    float l0 = bd[0], l1 = bd[1];
#pragma unroll
    for (int u = 0; u < 32; ++u) {
      float h = h3f[tid * 32 + u];
      l0 = fmaf(h, Wd[2 * u], l0);
      l1 = fmaf(h, Wd[2 * u + 1], l1);
    }
    float m = fmaxf(l0, l1);
    float e0 = __builtin_amdgcn_exp2f((l0 - m) * 1.44269504f);
    float e1 = __builtin_amdgcn_exp2f((l1 - m) * 1.44269504f);
    float inv = 1.f / (e0 + e1);
    out[(bbase + tid) * 2 + 0] = e0 * inv;
    out[(bbase + tid) * 2 + 1] = e1 * inv;
  }
}

extern "C" void kernel_launch(void* const* d_in, const int* in_sizes, int n_in,
                              void* d_out, int out_size, void* d_ws, size_t ws_size,
                              hipStream_t stream) {
  const float* inp  = (const float*)d_in[0];
  const float* Wemb = (const float*)d_in[1];
  const float* k0   = (const float*)d_in[2];
  const float* rk0  = (const float*)d_in[3];
  const float* b0   = (const float*)d_in[4];
  const float* k1   = (const float*)d_in[5];
  const float* rk1  = (const float*)d_in[6];
  const float* b1   = (const float*)d_in[7];
  const float* k2   = (const float*)d_in[8];
  const float* rk2  = (const float*)d_in[9];
  const float* b2   = (const float*)d_in[10];
  const float* k3   = (const float*)d_in[11];
  const float* rk3  = (const float*)d_in[12];
  const float* b3   = (const float*)d_in[13];
  const float* Wd   = (const float*)d_in[14];
  const float* bd   = (const float*)d_in[15];
  float* out = (float*)d_out;

  const int Btot = in_sizes[0] / (TT * FF);   // 4096
  dim3 grid(Btot / BT);                       // 256 blocks
  gru4<<<grid, 512, 0, stream>>>(inp, Wemb, k0, rk0, b0, k1, rk1, b1,
                                 k2, rk2, b2, k3, rk3, b3, Wd, bd, out);
}

// Round 4
// 342.928 us; speedup vs baseline: 2.3066x; 1.0662x over previous
//
#include <hip/hip_runtime.h>

// 4-layer GRU stack, B=4096, T=256. 256 persistent blocks x 768 threads
// (12 waves, 3 per SIMD), 16 batch rows per block (one M=16 MFMA tile).
//
// Wavefront pipelining across layers with PER-SIMD BALANCED jobs:
//   jobs = {L0 s0/s1 split by C-rows (4 half-jobs), L0 s2/s3 full,
//           L1 s0/s1, L2 s0/s1, L3 s0/s1}  -> 12 jobs, one per wave.
//   With wave->SIMD = w%4, every SIMD gets {half, full, full} = 60
//   transcendental instrs/step — exactly balanced.
// Layer l at step s computes time t = s - l; all cross-wave reads are
// previous-step values -> double-buffered h, ONE barrier per step.
//
// All jobs share ONE uniform shape (3 A-frags x {z,r,gx,gh} weight triples,
// zero-padded) so weight fragments live in shared variables -> no VGPR
// union blowup across role branches.

typedef __attribute__((ext_vector_type(8))) __bf16 bf16x8;
typedef __attribute__((ext_vector_type(4))) float f32x4;

#define TT 256
#define FF 20
#define BT 16
#define CH 64      // x chunk steps held in LDS
#define SH0 72     // h0 LDS row stride (bf16), padded from 64
#define SH1 40     // h1/h2/h3 LDS row stride, padded from 32
#define XSTR 648   // x_ch t-plane stride (bf16): 16*40 + 8 pad
#define NTHR 768

__device__ __forceinline__ f32x4 mfma16(bf16x8 a, bf16x8 b, f32x4 c) {
  return __builtin_amdgcn_mfma_f32_16x16x32_bf16(a, b, c, 0, 0, 0);
}

// NaN-free, clamp-free: correct limits at +-inf (rcp(inf)=0).
__device__ __forceinline__ float sigm(float x) {
  return __builtin_amdgcn_rcpf(1.f + __builtin_amdgcn_exp2f(-1.44269504f * x));
}
__device__ __forceinline__ float tanh_(float x) {
  return __builtin_amdgcn_rcpf(1.f + __builtin_amdgcn_exp2f(-2.88539008f * x)) * 2.f - 1.f;
}

// B-operand fragment from global row-major W[K][N]: lane holds col n, k=kbase+j.
__device__ __forceinline__ bf16x8 bfragW(const float* W, int Kreal, int N,
                                         int ncol, int kbase) {
  bf16x8 r;
#pragma unroll
  for (int j = 0; j < 8; ++j) {
    int k = kbase + j;
    r[j] = (__bf16)(k < Kreal ? W[k * N + ncol] : 0.f);
  }
  return r;
}

extern "C" __global__ void __launch_bounds__(NTHR, 3)
gru4(const float* __restrict__ inp, const float* __restrict__ Wemb,
     const float* __restrict__ k0, const float* __restrict__ rk0, const float* __restrict__ b0,
     const float* __restrict__ k1, const float* __restrict__ rk1, const float* __restrict__ b1,
     const float* __restrict__ k2, const float* __restrict__ rk2, const float* __restrict__ b2,
     const float* __restrict__ k3, const float* __restrict__ rk3, const float* __restrict__ b3,
     const float* __restrict__ Wd, const float* __restrict__ bd,
     float* __restrict__ out)
{
  __shared__ __align__(16) __bf16 x_ch[CH * XSTR];       // ~83 KB
  __shared__ __align__(16) __bf16 h0_lds[2][BT * SH0];
  __shared__ __align__(16) __bf16 h1_lds[2][BT * SH1];
  __shared__ __align__(16) __bf16 h2_lds[2][BT * SH1];
  __shared__ __align__(16) __bf16 h3_lds[2][BT * SH1];
  __shared__ __align__(16) float h3f[BT * 32];

  const int tid  = threadIdx.x;
  const int lane = tid & 63;
  const int w    = tid >> 6;        // wave 0..11
  const int col  = lane & 15;       // C col / B n / A m index
  const int kb   = (lane >> 4) * 8; // A/B k base within a k-tile
  const int rowq = (lane >> 4) * 4; // C row base (batch)
  const long bbase = (long)blockIdx.x * BT;
  const float* binp = inp + bbase * TT * FF;

  bf16x8 zf;
#pragma unroll
  for (int j = 0; j < 8; ++j) zf[j] = (__bf16)0.f;

  // ---- uniform per-wave job config (shared variables across all roles) ----
  bf16x8 Wz0 = zf, Wz1 = zf, Wz2 = zf;
  bf16x8 Wr0 = zf, Wr1 = zf, Wr2 = zf;
  bf16x8 Wgx0 = zf, Wgx1 = zf, Wgx2 = zf;
  bf16x8 Wgh0 = zf, Wgh1 = zf, Wgh2 = zf;
  float bz = 0.f, br = 0.f, bxh = 0.f, bhh = 0.f;
  const __bf16 *A0b = x_ch, *A1b = x_ch, *A2b = x_ch;
  int D0 = 0, D1 = 0, D2 = 0;
  __bf16* Wwr0 = (__bf16*)h3f;
  int WD = 0, wstride = SH1;
  int lay = 0;
  bool doLo = false, doHi = false, threeA = false;

  if (w < 6) {
    // L0: w0..w3 = row-halves of slices 0,1; w4,w5 = full slices 2,3.
    lay = 0; threeA = true;
    const int sl = (w < 4) ? (w >> 1) : (w - 2);
    doLo = (w >= 4) || ((w & 1) == 0);
    doHi = (w >= 4) || ((w & 1) == 1);
    const int u = sl * 16 + col;
    Wz0 = bfragW(k0, 23, 192, u, kb);
    Wz1 = bfragW(rk0, 64, 192, u, kb);
    Wz2 = bfragW(rk0, 64, 192, u, 32 + kb);
    Wr0 = bfragW(k0, 23, 192, 64 + u, kb);
    Wr1 = bfragW(rk0, 64, 192, 64 + u, kb);
    Wr2 = bfragW(rk0, 64, 192, 64 + u, 32 + kb);
    Wgx0 = bfragW(k0, 23, 192, 128 + u, kb);
    Wgh1 = bfragW(rk0, 64, 192, 128 + u, kb);
    Wgh2 = bfragW(rk0, 64, 192, 128 + u, 32 + kb);
    bz  = b0[u] + b0[192 + u];
    br  = b0[64 + u] + b0[192 + 64 + u];
    bxh = b0[128 + u];
    bhh = b0[192 + 128 + u];
    A1b = &h0_lds[0][col * SH0 + kb];      D1 = BT * SH0;
    A2b = &h0_lds[0][col * SH0 + 32 + kb]; D2 = BT * SH0;
    Wwr0 = &h0_lds[0][rowq * SH0 + sl * 16 + col];
    WD = BT * SH0; wstride = SH0;
  } else if (w < 8) {
    // L1: slices 0,1 full.
    lay = 1; threeA = true; doLo = doHi = true;
    const int u = (w - 6) * 16 + col;
    Wz0 = bfragW(k1, 64, 96, u, kb);
    Wz1 = bfragW(k1, 64, 96, u, 32 + kb);
    Wz2 = bfragW(rk1, 32, 96, u, kb);
    Wr0 = bfragW(k1, 64, 96, 32 + u, kb);
    Wr1 = bfragW(k1, 64, 96, 32 + u, 32 + kb);
    Wr2 = bfragW(rk1, 32, 96, 32 + u, kb);
    Wgx0 = bfragW(k1, 64, 96, 64 + u, kb);
    Wgx1 = bfragW(k1, 64, 96, 64 + u, 32 + kb);
    Wgh2 = bfragW(rk1, 32, 96, 64 + u, kb);
    bz  = b1[u] + b1[96 + u];
    br  = b1[32 + u] + b1[96 + 32 + u];
    bxh = b1[64 + u];
    bhh = b1[96 + 64 + u];
    A0b = &h0_lds[0][col * SH0 + kb];      D0 = BT * SH0;
    A1b = &h0_lds[0][col * SH0 + 32 + kb]; D1 = BT * SH0;
    A2b = &h1_lds[0][col * SH1 + kb];      D2 = BT * SH1;
    Wwr0 = &h1_lds[0][rowq * SH1 + (w - 6) * 16 + col];
    WD = BT * SH1; wstride = SH1;
  } else if (w < 10) {
    // L2: slices 0,1 full.
    lay = 2; threeA = false; doLo = doHi = true;
    const int u = (w - 8) * 16 + col;
    Wz0 = bfragW(k2, 32, 96, u, kb);
    Wz1 = bfragW(rk2, 32, 96, u, kb);
    Wr0 = bfragW(k2, 32, 96, 32 + u, kb);
    Wr1 = bfragW(rk2, 32, 96, 32 + u, kb);
    Wgx0 = bfragW(k2, 32, 96, 64 + u, kb);
    Wgh1 = bfragW(rk2, 32, 96, 64 + u, kb);
    bz  = b2[u] + b2[96 + u];
    br  = b2[32 + u] + b2[96 + 32 + u];
    bxh = b2[64 + u];
    bhh = b2[96 + 64 + u];
    A0b = &h1_lds[0][col * SH1 + kb]; D0 = BT * SH1;
    A1b = &h2_lds[0][col * SH1 + kb]; D1 = BT * SH1;
    A2b = A1b; D2 = D1;
    Wwr0 = &h2_lds[0][rowq * SH1 + (w - 8) * 16 + col];
    WD = BT * SH1; wstride = SH1;
  } else {
    // L3: slices 0,1 full.
    lay = 3; threeA = false; doLo = doHi = true;
    const int u = (w - 10) * 16 + col;
    Wz0 = bfragW(k3, 32, 96, u, kb);
    Wz1 = bfragW(rk3, 32, 96, u, kb);
    Wr0 = bfragW(k3, 32, 96, 32 + u, kb);
    Wr1 = bfragW(rk3, 32, 96, 32 + u, kb);
    Wgx0 = bfragW(k3, 32, 96, 64 + u, kb);
    Wgh1 = bfragW(rk3, 32, 96, 64 + u, kb);
    bz  = b3[u] + b3[96 + u];
    br  = b3[32 + u] + b3[96 + 32 + u];
    bxh = b3[64 + u];
    bhh = b3[96 + 64 + u];
    A0b = &h2_lds[0][col * SH1 + kb]; D0 = BT * SH1;
    A1b = &h3_lds[0][col * SH1 + kb]; D1 = BT * SH1;
    A2b = A1b; D2 = D1;
    Wwr0 = &h3_lds[0][rowq * SH1 + (w - 10) * 16 + col];
    WD = BT * SH1; wstride = SH1;
  }

  const __bf16* xb = &x_ch[col * 40 + kb];  // L0 x A-frag base (per t-plane)

  // ------------- zero-init h state -------------
  {
    __bf16* p0 = (__bf16*)h0_lds;
    for (int i = tid; i < 2 * BT * SH0; i += NTHR) p0[i] = (__bf16)0.f;
    __bf16* p1 = (__bf16*)h1_lds;
    __bf16* p2 = (__bf16*)h2_lds;
    __bf16* p3 = (__bf16*)h3_lds;
    for (int i = tid; i < 2 * BT * SH1; i += NTHR) {
      p1[i] = (__bf16)0.f; p2[i] = (__bf16)0.f; p3[i] = (__bf16)0.f;
    }
  }
  float hreg[4] = {0.f, 0.f, 0.f, 0.f};
  __syncthreads();

  for (int s = 0; s < TT + 3; ++s) {
    // ---- bulk x staging every CH steps ----
    if ((s & (CH - 1)) == 0 && s < TT) {
      for (int idx = tid; idx < BT * CH; idx += NTHR) {
        const int row = idx >> 6;          // CH = 64
        const int tg  = idx & (CH - 1);
        const float* p = binp + ((long)row * TT + s + tg) * FF;
        float4 v0 = *(const float4*)(p);
        float4 v1 = *(const float4*)(p + 4);
        float4 v2 = *(const float4*)(p + 8);
        float4 v3 = *(const float4*)(p + 12);
        float4 v4 = *(const float4*)(p + 16);
        float4 e  = *(const float4*)(Wemb + 4 * (int)v0.y);
        __bf16* d = &x_ch[tg * XSTR + row * 40];
        bf16x8 q0 = {(__bf16)v0.x, (__bf16)v0.z, (__bf16)v0.w, (__bf16)v1.x,
                     (__bf16)v1.y, (__bf16)v1.z, (__bf16)v1.w, (__bf16)v2.x};
        bf16x8 q1 = {(__bf16)v2.y, (__bf16)v2.z, (__bf16)v2.w, (__bf16)v3.x,
                     (__bf16)v3.y, (__bf16)v3.z, (__bf16)v3.w, (__bf16)v4.x};
        bf16x8 q2 = {(__bf16)v4.y, (__bf16)v4.z, (__bf16)v4.w, (__bf16)e.x,
                     (__bf16)e.y,  (__bf16)e.z,  (__bf16)e.w,  (__bf16)0.f};
        *(bf16x8*)(d)      = q0;
        *(bf16x8*)(d + 8)  = q1;
        *(bf16x8*)(d + 16) = q2;
        *(bf16x8*)(d + 24) = zf;
      }
      __syncthreads();
    }

    const int pb = (s + 1) & 1;  // read buffer (previous step's writes)
    const int qb = s & 1;        // write buffer
    const int t  = s - lay;

    if (t >= 0 && t < TT) {
      const __bf16* a0p = (lay == 0) ? (xb + (s & (CH - 1)) * XSTR)
                                     : (A0b + pb * D0);
      bf16x8 A0 = *(const bf16x8*)a0p;
      bf16x8 A1 = *(const bf16x8*)(A1b + pb * D1);
      f32x4 az  = {bz, bz, bz, bz};
      f32x4 ar  = {br, br, br, br};
      f32x4 axh = {bxh, bxh, bxh, bxh};
      f32x4 ahh = {bhh, bhh, bhh, bhh};
      az  = mfma16(A0, Wz0, az);   az  = mfma16(A1, Wz1, az);
      ar  = mfma16(A0, Wr0, ar);   ar  = mfma16(A1, Wr1, ar);
      axh = mfma16(A0, Wgx0, axh); axh = mfma16(A1, Wgx1, axh);
      ahh = mfma16(A0, Wgh0, ahh); ahh = mfma16(A1, Wgh1, ahh);
      if (threeA) {
        bf16x8 A2 = *(const bf16x8*)(A2b + pb * D2);
        az  = mfma16(A2, Wz2, az);
        ar  = mfma16(A2, Wr2, ar);
        axh = mfma16(A2, Wgx2, axh);
        ahh = mfma16(A2, Wgh2, ahh);
      }
      __bf16* wr = Wwr0 + qb * WD;

#define GATE(r) { \
        float z  = sigm(az[r]); \
        float rg = sigm(ar[r]); \
        float hc = tanh_(fmaf(rg, ahh[r], axh[r])); \
        float hn = fmaf(z, hreg[r] - hc, hc); \
        hreg[r] = hn; \
        wr[(r) * wstride] = (__bf16)hn; }

      if (doLo) { GATE(0); GATE(1); }
      if (doHi) { GATE(2); GATE(3); }
#undef GATE
    }

    __syncthreads();   // single per-step barrier
  }

  // ------------- epilogue: logits + softmax -------------
  if (w >= 10) {
#pragma unroll
    for (int r = 0; r < 4; ++r)
      h3f[(rowq + r) * 32 + (w - 10) * 16 + col] = hreg[r];
  }
  __syncthreads();

  if (tid < BT) {
    float l0 = bd[0], l1 = bd[1];
#pragma unroll
    for (int u = 0; u < 32; ++u) {
      float h = h3f[tid * 32 + u];
      l0 = fmaf(h, Wd[2 * u], l0);
      l1 = fmaf(h, Wd[2 * u + 1], l1);
    }
    float m = fmaxf(l0, l1);
    float e0 = __builtin_amdgcn_exp2f((l0 - m) * 1.44269504f);
    float e1 = __builtin_amdgcn_exp2f((l1 - m) * 1.44269504f);
    float inv = 1.f / (e0 + e1);
    out[(bbase + tid) * 2 + 0] = e0 * inv;
    out[(bbase + tid) * 2 + 1] = e1 * inv;
  }
}

extern "C" void kernel_launch(void* const* d_in, const int* in_sizes, int n_in,
                              void* d_out, int out_size, void* d_ws, size_t ws_size,
                              hipStream_t stream) {
  const float* inp  = (const float*)d_in[0];
  const float* Wemb = (const float*)d_in[1];
  const float* k0   = (const float*)d_in[2];
  const float* rk0  = (const float*)d_in[3];
  const float* b0   = (const float*)d_in[4];
  const float* k1   = (const float*)d_in[5];
  const float* rk1  = (const float*)d_in[6];
  const float* b1   = (const float*)d_in[7];
  const float* k2   = (const float*)d_in[8];
  const float* rk2  = (const float*)d_in[9];
  const float* b2   = (const float*)d_in[10];
  const float* k3   = (const float*)d_in[11];
  const float* rk3  = (const float*)d_in[12];
  const float* b3   = (const float*)d_in[13];
  const float* Wd   = (const float*)d_in[14];
  const float* bd   = (const float*)d_in[15];
  float* out = (float*)d_out;

  const int Btot = in_sizes[0] / (TT * FF);   // 4096
  dim3 grid(Btot / BT);                       // 256 blocks
  gru4<<<grid, NTHR, 0, stream>>>(inp, Wemb, k0, rk0, b0, k1, rk1, b1,
                                  k2, rk2, b2, k3, rk3, b3, Wd, bd, out);
}